// Round 1
// baseline (27013.367 us; speedup 1.0000x reference)
//
#include <hip/hip_runtime.h>

// ============================================================================
// LSTM (B=256, S=512, H=1024, X=10, C=10) on MI355X.
// Design (round 1):
//  - one persistent cooperative kernel, 256 blocks x 256 threads (1 block/CU)
//  - block (r, jt): batch rows [64r, 64r+64), hidden units [16jt, 16jt+16)
//  - wave w (0..3) = gate w (g,i,f,o); B-frags (Wh f16) preloaded into VGPRs
//    (128 VGPR/lane) and reused for all 512 timesteps
//  - h stored f16 in ws, double-buffered; per-row-group flag sync
//    (release atomicAdd / relaxed spin + threadfence), 1 sync per step
//  - A (h tile) staged to LDS via global_load_lds(16B), 8 chunks,
//    prefetch-next-chunk / compute / __syncthreads overlap
//  - gate math fp32, c-state in registers; final h also written fp32
//  - separate fp32 kernel: p = h@Wp + bp, log_softmax
// ============================================================================

typedef _Float16 half8 __attribute__((ext_vector_type(8)));
typedef float f32x4 __attribute__((ext_vector_type(4)));

#define HD 1024
#define SS 512

// ws layout (bytes)
#define WS_CTR     0         // 4 x u32 row-group counters
#define WS_FLAG    256       // int: nonzero => x is int32, zero => int64
#define WS_WXB     1024      // [4][10][1024] f32 = 163840  (Wx[gate][xval][j] + b[gate][j])
#define WS_HBUF0   262144    // [256][1024] f16 = 512KB
#define WS_HBUF1   786432    // [256][1024] f16 = 512KB
#define WS_HFINAL  1310720   // [256][1024] f32 = 1MB

__device__ __forceinline__ float fast_sigmoid(float x) {
    return __builtin_amdgcn_rcpf(1.f + __expf(-x));
}
__device__ __forceinline__ float fast_tanh(float x) {
    float e = __expf(-2.f * x);
    return (1.f - e) * __builtin_amdgcn_rcpf(1.f + e);
}

// global -> LDS direct copy, 16B per lane. LDS dest must be wave-uniform base.
__device__ __forceinline__ void stage16(const _Float16* g, _Float16* l) {
    __builtin_amdgcn_global_load_lds(
        (const __attribute__((address_space(1))) unsigned int*)g,
        (__attribute__((address_space(3))) unsigned int*)l,
        16, 0, 0);
}

// x-dtype detection: if x is int64 (little endian), all odd 32-bit words are 0.
__global__ void detect_kernel(const int* __restrict__ xw, int* __restrict__ flag) {
    int i = blockIdx.x * blockDim.x + threadIdx.x;   // 0..4095
    if (xw[2 * i + 1] != 0) atomicOr(flag, 1);
}

__global__ void wxb_kernel(const float* __restrict__ Wxg, const float* __restrict__ bg,
                           const float* __restrict__ Wxi, const float* __restrict__ bi,
                           const float* __restrict__ Wxf, const float* __restrict__ bf,
                           const float* __restrict__ Wxo, const float* __restrict__ bo,
                           float* __restrict__ WxB) {
    int i = blockIdx.x * blockDim.x + threadIdx.x;   // < 40960
    if (i >= 4 * 10 * HD) return;
    int g = i / (10 * HD), r = i % (10 * HD), v = r / HD, j = r % HD;
    const float* Wx = (g == 0) ? Wxg : (g == 1) ? Wxi : (g == 2) ? Wxf : Wxo;
    const float* bb = (g == 0) ? bg  : (g == 1) ? bi  : (g == 2) ? bf  : bo;
    WxB[i] = Wx[v * HD + j] + bb[j];
}

__global__ void __launch_bounds__(256, 1)
lstm_main(const int* __restrict__ xraw, const float* __restrict__ Whg,
          const float* __restrict__ Whi, const float* __restrict__ Whf,
          const float* __restrict__ Who, unsigned char* __restrict__ ws)
{
    extern __shared__ char smem[];
    _Float16* A_lds = (_Float16*)smem;           // [kc=128][m=64][8] f16 = 128KB
    float*    zbuf  = (float*)(smem + 131072);   // [m=64][g=4][u=16] f32 = 16KB

    unsigned int* ctr = (unsigned int*)(ws + WS_CTR);
    const int is32 = (*(const int*)(ws + WS_FLAG)) != 0;
    const float* WxB = (const float*)(ws + WS_WXB);
    _Float16* hb0 = (_Float16*)(ws + WS_HBUF0);
    _Float16* hb1 = (_Float16*)(ws + WS_HBUF1);
    float* hfinal = (float*)(ws + WS_HFINAL);

    const int tid = threadIdx.x;
    const int w   = tid >> 6;        // wave id == gate id
    const int l   = tid & 63;
    const int bid = blockIdx.x;
    // XCD-aware mapping: xcd = bid % 8 (heuristic). Row group r uses XCDs {2r, 2r+1}.
    const int r   = (bid & 7) >> 1;                 // row group 0..3 (64 batch rows)
    const int jt  = ((bid >> 3) << 1) | (bid & 1);  // hidden tile 0..63 (16 units)
    const int row0 = r << 6;
    const int col0 = jt << 4;

    const float* Wg = (w == 0) ? Whg : (w == 1) ? Whi : (w == 2) ? Whf : Who;

    const int u  = l & 15;           // MFMA n / unit within tile
    const int kg = (l >> 4) << 3;    // MFMA k sub-chunk base

    // ---- preload B fragments (Wh columns for this block, this gate) into VGPRs ----
    // B[k][n]: lane holds k = kk*32 + (l>>4)*8 + j, n = l&15
    half8 bfrag[32];
#pragma unroll
    for (int kk = 0; kk < 32; ++kk) {
        const float* src = Wg + (size_t)(kk * 32 + kg) * HD + col0 + u;
#pragma unroll
        for (int j = 0; j < 8; ++j)
            bfrag[kk][j] = (_Float16)src[(size_t)j * HD];
    }

    // c-state: thread owns pairs p = tid + 256*q -> (m = p>>4, u = p&15)
    float cst[4] = {0.f, 0.f, 0.f, 0.f};
    unsigned int* ctr_r = ctr + r;

    for (int t = 0; t < SS; ++t) {
        const _Float16* hsrc = (t & 1) ? hb1 : hb0;
        _Float16*       hdst = (t & 1) ? hb0 : hb1;

        // ---- wait until all 64 blocks of this row group finished step t-1 ----
        const unsigned int target = (unsigned int)t << 6;
        while (__hip_atomic_load(ctr_r, __ATOMIC_RELAXED, __HIP_MEMORY_SCOPE_AGENT) < target)
            __builtin_amdgcn_s_sleep(2);
        __threadfence();          // acquire: make producers' h stores visible
        __syncthreads();

        f32x4 acc[4];
#pragma unroll
        for (int mt = 0; mt < 4; ++mt) acc[mt] = (f32x4){0.f, 0.f, 0.f, 0.f};

        const _Float16* arow = hsrc + (size_t)(row0 + l) * HD;

        // ---- stage chunk 0 (A tile k in [0,128)) ----
#pragma unroll
        for (int i = 0; i < 4; ++i) {
            int q = (w << 2) + i;                    // kc index
            stage16(arow + (q << 3), A_lds + (q << 9));
        }
        __syncthreads();   // drains vmcnt(0) + barrier: chunk 0 visible

        // ---- 8 chunks: prefetch next, compute current ----
#pragma unroll
        for (int c = 0; c < 8; ++c) {
            if (c < 7) {
#pragma unroll
                for (int i = 0; i < 4; ++i) {
                    int q = ((c + 1) << 4) + (w << 2) + i;
                    stage16(arow + (q << 3), A_lds + (q << 9));
                }
            }
#pragma unroll
            for (int kkl = 0; kkl < 4; ++kkl) {
                const int kk = (c << 2) + kkl;
                const int abase = ((kk << 2) + (l >> 4)) * 512 + (l & 15) * 8;
#pragma unroll
                for (int mt = 0; mt < 4; ++mt) {
                    half8 a = *(const half8*)(A_lds + abase + mt * 128);
                    acc[mt] = __builtin_amdgcn_mfma_f32_16x16x32_f16(a, bfrag[kk], acc[mt], 0, 0, 0);
                }
            }
            __syncthreads();   // next chunk's loads drained + visible
        }

        // ---- exchange z across waves (each wave holds one gate) ----
        // D layout: row m = mt*16 + (l>>4)*4 + rr, col n = l&15
#pragma unroll
        for (int mt = 0; mt < 4; ++mt)
#pragma unroll
            for (int rr = 0; rr < 4; ++rr)
                zbuf[((mt << 4) + ((l >> 4) << 2) + rr) * 64 + (w << 4) + u] = acc[mt][rr];
        __syncthreads();

        // ---- gates, c/h update ----
        const int lastt = (t == SS - 1);
#pragma unroll
        for (int q = 0; q < 4; ++q) {
            const int p = tid + (q << 8);
            const int m = p >> 4, uu = p & 15;
            const int brow = row0 + m;
            const size_t xi = (size_t)brow * SS + t;
            const int xv = is32 ? xraw[xi] : xraw[xi << 1];   // int64: low word
            const float* wxp = WxB + (size_t)xv * HD + col0 + uu;
            const float* zp  = zbuf + (m << 6) + uu;
            float zg = zp[0]  + wxp[0];
            float zi = zp[16] + wxp[10240];
            float zf = zp[32] + wxp[20480];
            float zo = zp[48] + wxp[30720];
            float gg = fast_tanh(zg);
            float ii = fast_sigmoid(zi);
            float ff = fast_sigmoid(zf);
            float oo = fast_sigmoid(zo);
            float cv = gg * ii + cst[q] * ff;
            cst[q] = cv;
            float hv = fast_tanh(cv) * oo;
            hdst[(size_t)brow * HD + col0 + uu] = (_Float16)hv;
            if (lastt) hfinal[(size_t)brow * HD + col0 + uu] = hv;
        }
        __threadfence();    // release: push h stores toward coherence point
        __syncthreads();
        if (tid == 0)
            __hip_atomic_fetch_add(ctr_r, 1u, __ATOMIC_RELEASE, __HIP_MEMORY_SCOPE_AGENT);
    }
}

// p = h @ Wp + bp; out = log_softmax(p). One block per batch row.
__global__ void proj_kernel(const float* __restrict__ hfin, const float* __restrict__ Wp,
                            const float* __restrict__ bp, float* __restrict__ out)
{
    const int b = blockIdx.x;
    const int tid = threadIdx.x;
    float acc[10];
#pragma unroll
    for (int c = 0; c < 10; ++c) acc[c] = 0.f;
#pragma unroll
    for (int q = 0; q < 4; ++q) {
        int k = tid + (q << 8);
        float hv = hfin[b * HD + k];
#pragma unroll
        for (int c = 0; c < 10; ++c) acc[c] += hv * Wp[k * 10 + c];
    }
#pragma unroll
    for (int off = 32; off >= 1; off >>= 1)
#pragma unroll
        for (int c = 0; c < 10; ++c) acc[c] += __shfl_down(acc[c], off);

    __shared__ float red[4][10];
    const int wv = tid >> 6, ln = tid & 63;
    if (ln == 0)
#pragma unroll
        for (int c = 0; c < 10; ++c) red[wv][c] = acc[c];
    __syncthreads();
    if (tid == 0) {
        float p[10];
#pragma unroll
        for (int c = 0; c < 10; ++c)
            p[c] = red[0][c] + red[1][c] + red[2][c] + red[3][c] + bp[c];
        float mx = p[0];
#pragma unroll
        for (int c = 1; c < 10; ++c) mx = fmaxf(mx, p[c]);
        float s = 0.f;
#pragma unroll
        for (int c = 0; c < 10; ++c) s += __expf(p[c] - mx);
        float lse = mx + logf(s);
#pragma unroll
        for (int c = 0; c < 10; ++c) out[b * 10 + c] = p[c] - lse;
    }
}

extern "C" void kernel_launch(void* const* d_in, const int* in_sizes, int n_in,
                              void* d_out, int out_size, void* d_ws, size_t ws_size,
                              hipStream_t stream) {
    const int*   x   = (const int*)d_in[0];
    const float* Wxg = (const float*)d_in[1];
    const float* Whg = (const float*)d_in[2];
    const float* bg  = (const float*)d_in[3];
    const float* Wxi = (const float*)d_in[4];
    const float* Whi = (const float*)d_in[5];
    const float* bi  = (const float*)d_in[6];
    const float* Wxf = (const float*)d_in[7];
    const float* Whf = (const float*)d_in[8];
    const float* bf_ = (const float*)d_in[9];
    const float* Wxo = (const float*)d_in[10];
    const float* Who = (const float*)d_in[11];
    const float* bo  = (const float*)d_in[12];
    const float* Wp  = (const float*)d_in[13];
    const float* bp  = (const float*)d_in[14];
    unsigned char* ws = (unsigned char*)d_ws;
    float* out = (float*)d_out;

    // zero sync counters + dtype flag; zero h_0
    hipMemsetAsync(ws, 0, 1024, stream);
    hipMemsetAsync(ws + WS_HBUF0, 0, 512 * 1024, stream);

    detect_kernel<<<16, 256, 0, stream>>>(x, (int*)(ws + WS_FLAG));
    wxb_kernel<<<160, 256, 0, stream>>>(Wxg, bg, Wxi, bi, Wxf, bf_, Wxo, bo,
                                        (float*)(ws + WS_WXB));

    const unsigned int smem_bytes = 147456;   // 128KB A + 16KB zbuf
    hipFuncSetAttribute((const void*)lstm_main,
                        hipFuncAttributeMaxDynamicSharedMemorySize, (int)smem_bytes);

    void* args[] = { (void*)&x, (void*)&Whg, (void*)&Whi, (void*)&Whf, (void*)&Who, (void*)&ws };
    hipError_t err = hipLaunchCooperativeKernel((const void*)lstm_main, dim3(256), dim3(256),
                                                args, smem_bytes, stream);
    if (err != hipSuccess) {
        // fallback: 1 block/CU (144KB LDS) on a 256-CU device is co-resident in practice
        lstm_main<<<dim3(256), dim3(256), smem_bytes, stream>>>(x, Whg, Whi, Whf, Who, ws);
    }

    proj_kernel<<<256, 256, 0, stream>>>((const float*)(ws + WS_HFINAL), Wp, bp, out);
}

// Round 2
// 5272.853 us; speedup vs baseline: 5.1231x; 5.1231x over previous
//
#include <hip/hip_runtime.h>

// ============================================================================
// LSTM (B=256, S=512, H=1024, X=10, C=10) on MI355X — round 2.
// Key change vs round 1: ALL per-step data flow is XCD-local.
//  - each XCD owns batch rows [32*xcd, 32*xcd+32) x all 1024 hidden units
//  - 32 blocks per XCD (1/CU, forced by 96KB dyn-LDS), each block owns 32
//    units x 4 gates; wave w = gate w
//  - blocks read HW_REG_XCC_ID and self-assign unit slots via atomicAdd, so
//    correctness does not depend on the bid->XCD mapping (coop launch +
//    1 block/CU pigeonholes exactly 32 blocks per XCD)
//  - Wh f16 fragments resident in VGPRs (256 regs/lane) for all 512 steps
//  - h exchange: plain stores (write-through to local L2) + s_waitcnt
//    vmcnt(0) + relaxed agent atomicAdd; consumers spin on counter (wave 0
//    only), then read A with sc0 (L1-bypass) loads straight from local L2.
//    NO __threadfence (no L2 writeback/invalidate) anywhere in the loop.
//  - A streamed with counted vmcnt(8) double-buffered 4-kk chunks,
//    sched_barrier(0) after each waitcnt (rule: MFMA hoists past asm waits)
// ============================================================================

typedef _Float16 half8 __attribute__((ext_vector_type(8)));
typedef float f32x4 __attribute__((ext_vector_type(4)));

#define HD 1024
#define SS 512

// ws layout (bytes)
#define WS_CTR    0         // 8 step-counters, stride 128B (one per XCD)
#define WS_SLOT   2048      // 8 slot-claim counters
#define WS_FLAG   4096      // x dtype flag
#define WS_WXB    8192      // [4][10][1024] f32 = 163840
#define WS_HBUF0  262144    // [256][1024] f16 = 512KB
#define WS_HBUF1  786432    // [256][1024] f16 = 512KB
#define WS_HFINAL 1310720   // [256][1024] f32 = 1MB

__device__ __forceinline__ float fast_sigmoid(float x) {
    return __builtin_amdgcn_rcpf(1.f + __expf(-x));
}
__device__ __forceinline__ float fast_tanh(float x) {
    float e = __expf(-2.f * x);
    return (1.f - e) * __builtin_amdgcn_rcpf(1.f + e);
}

// 16B load, L1-bypass (sc0) -> served from the XCD's L2 (coherent intra-XCD
// with write-through stores from other CUs on this XCD).
__device__ __forceinline__ void issue_chunk(half8 (&buf)[2][4], const _Float16* abase, int cbase) {
#pragma unroll
    for (int mt = 0; mt < 2; ++mt)
#pragma unroll
        for (int kq = 0; kq < 4; ++kq)
            asm volatile("global_load_dwordx4 %0, %1, off sc0"
                         : "=v"(buf[mt][kq])
                         : "v"(abase + (size_t)mt * 16 * HD + (size_t)(cbase + kq) * 32));
}

// x-dtype detection: if x is int64 (little endian), all odd 32-bit words are 0.
__global__ void detect_kernel(const int* __restrict__ xw, int* __restrict__ flag) {
    int i = blockIdx.x * blockDim.x + threadIdx.x;   // 0..4095
    if (xw[2 * i + 1] != 0) atomicOr(flag, 1);
}

__global__ void wxb_kernel(const float* __restrict__ Wxg, const float* __restrict__ bg,
                           const float* __restrict__ Wxi, const float* __restrict__ bi,
                           const float* __restrict__ Wxf, const float* __restrict__ bf,
                           const float* __restrict__ Wxo, const float* __restrict__ bo,
                           float* __restrict__ WxB) {
    int i = blockIdx.x * blockDim.x + threadIdx.x;   // < 40960
    if (i >= 4 * 10 * HD) return;
    int g = i / (10 * HD), r = i % (10 * HD), v = r / HD, j = r % HD;
    const float* Wx = (g == 0) ? Wxg : (g == 1) ? Wxi : (g == 2) ? Wxf : Wxo;
    const float* bb = (g == 0) ? bg  : (g == 1) ? bi  : (g == 2) ? bf  : bo;
    WxB[i] = Wx[v * HD + j] + bb[j];
}

__global__ void __launch_bounds__(256, 1)
lstm_main(const int* __restrict__ xraw, const float* __restrict__ Whg,
          const float* __restrict__ Whi, const float* __restrict__ Whf,
          const float* __restrict__ Who, unsigned char* __restrict__ ws)
{
    extern __shared__ char smem[];           // 96KB requested (forces 1 block/CU)
    float* zbuf = (float*)smem;              // [32 rows][4 gates][32 units] f32 = 16KB
    __shared__ int s_info;

    const int tid = threadIdx.x;
    const int w = tid >> 6, l = tid & 63;

    // ---- discover physical XCD, claim a unit-slot on it ----
    if (tid == 0) {
        unsigned int xcc;
        asm volatile("s_getreg_b32 %0, hwreg(HW_REG_XCC_ID)" : "=s"(xcc));
        unsigned int* slotc = (unsigned int*)(ws + WS_SLOT);
        unsigned int slot = __hip_atomic_fetch_add(&slotc[xcc & 7], 1u,
                                                   __ATOMIC_RELAXED, __HIP_MEMORY_SCOPE_AGENT);
        s_info = (int)(((xcc & 7) << 8) | (slot & 31));
    }
    __syncthreads();
    const int xcd  = (s_info >> 8) & 7;
    const int slot = s_info & 31;            // 0..31 (exactly 32 blocks/XCD)

    const int row0 = xcd << 5;               // 32 batch rows
    const int col0 = slot << 5;              // 32 hidden units
    const int u  = l & 15;
    const int kg = (l >> 4) << 3;

    const float* Wg = (w == 0) ? Whg : (w == 1) ? Whi : (w == 2) ? Whf : Who;
    const int is32 = (*(const int*)(ws + WS_FLAG)) != 0;
    const float* WxB = (const float*)(ws + WS_WXB);
    _Float16* hb0 = (_Float16*)(ws + WS_HBUF0);
    _Float16* hb1 = (_Float16*)(ws + WS_HBUF1);
    float* hfinal = (float*)(ws + WS_HFINAL);
    unsigned int* ctr = (unsigned int*)(ws + WS_CTR + xcd * 128);

    // ---- preload B fragments (this block's Wh columns, this wave's gate) ----
    // lane l, elem j of bfrag[nt][kk] = Wh[k = kk*32 + (l>>4)*8 + j][col0 + nt*16 + (l&15)]
    half8 bfrag[2][32];
#pragma unroll
    for (int nt = 0; nt < 2; ++nt)
#pragma unroll
        for (int kk = 0; kk < 32; ++kk) {
            const float* src = Wg + (size_t)(kk * 32 + kg) * HD + col0 + nt * 16 + u;
#pragma unroll
            for (int j = 0; j < 8; ++j)
                bfrag[nt][kk][j] = (_Float16)src[(size_t)j * HD];
        }

    // c-state: thread owns (row m = p>>5, unit uu = p&31) for p = tid + 256q
    float cst[4] = {0.f, 0.f, 0.f, 0.f};

    for (int t = 0; t < SS; ++t) {
        const _Float16* hsrc = (t & 1) ? hb1 : hb0;
        _Float16*       hdst = (t & 1) ? hb0 : hb1;

        // ---- wait for all 32 blocks of this XCD to finish step t-1 ----
        if (tid < 64) {
            const unsigned int target = (unsigned int)t << 5;
            while (__hip_atomic_load(ctr, __ATOMIC_RELAXED, __HIP_MEMORY_SCOPE_AGENT) < target)
                __builtin_amdgcn_s_sleep(1);
        }
        __syncthreads();

        // ---- A-frag streaming + MFMA (counted-vmcnt double buffer) ----
        // lane A addr: row = row0 + (l&15) + 16*mt, k = kk*32 + (l>>4)*8 + j
        const _Float16* abase = hsrc + (size_t)(row0 + u) * HD + kg;

        f32x4 acc[2][2];
#pragma unroll
        for (int mt = 0; mt < 2; ++mt)
#pragma unroll
            for (int nt = 0; nt < 2; ++nt)
                acc[mt][nt] = (f32x4){0.f, 0.f, 0.f, 0.f};

        half8 aA[2][4], aB[2][4];
        issue_chunk(aA, abase, 0);                       // chunk 0 (kk 0..3)
#pragma unroll
        for (int c = 0; c < 8; ++c) {
            if (c < 7) {
                if ((c & 1) == 0) issue_chunk(aB, abase, (c + 1) * 4);
                else              issue_chunk(aA, abase, (c + 1) * 4);
            }
            if (c < 7) asm volatile("s_waitcnt vmcnt(8)" ::: "memory");
            else       asm volatile("s_waitcnt vmcnt(0)" ::: "memory");
            __builtin_amdgcn_sched_barrier(0);
#pragma unroll
            for (int kq = 0; kq < 4; ++kq) {
                const int kk = c * 4 + kq;
#pragma unroll
                for (int mt = 0; mt < 2; ++mt)
#pragma unroll
                    for (int nt = 0; nt < 2; ++nt)
                        acc[mt][nt] = __builtin_amdgcn_mfma_f32_16x16x32_f16(
                            (c & 1) ? aB[mt][kq] : aA[mt][kq],
                            bfrag[nt][kk], acc[mt][nt], 0, 0, 0);
            }
        }

        // ---- exchange z across waves (wave w holds gate w) ----
        // D layout: row = mt*16 + (l>>4)*4 + rr, col = l&15 (verified round 1)
#pragma unroll
        for (int mt = 0; mt < 2; ++mt)
#pragma unroll
            for (int nt = 0; nt < 2; ++nt)
#pragma unroll
                for (int rr = 0; rr < 4; ++rr)
                    zbuf[(mt * 16 + ((l >> 4) << 2) + rr) * 128 + w * 32 + nt * 16 + u]
                        = acc[mt][nt][rr];
        __syncthreads();

        // ---- gates, c/h update ----
        const int lastt = (t == SS - 1);
#pragma unroll
        for (int q = 0; q < 4; ++q) {
            const int p = tid + (q << 8);
            const int m = p >> 5, uu = p & 31;
            const int brow = row0 + m;
            const size_t xi = (size_t)brow * SS + t;
            const int xv = is32 ? xraw[xi] : xraw[xi << 1];   // int64: low word
            const int j = col0 + uu;
            const float* zr = zbuf + (m << 7);
            float zg = zr[uu]       + WxB[(size_t)xv * HD + j];
            float zi = zr[32 + uu]  + WxB[(size_t)(10 + xv) * HD + j];
            float zf = zr[64 + uu]  + WxB[(size_t)(20 + xv) * HD + j];
            float zo = zr[96 + uu]  + WxB[(size_t)(30 + xv) * HD + j];
            float gg = fast_tanh(zg);
            float ii = fast_sigmoid(zi);
            float ff = fast_sigmoid(zf);
            float oo = fast_sigmoid(zo);
            float cv = gg * ii + cst[q] * ff;
            cst[q] = cv;
            float hv = fast_tanh(cv) * oo;
            hdst[(size_t)brow * HD + j] = (_Float16)hv;
            if (lastt) hfinal[(size_t)brow * HD + j] = hv;
        }

        // ---- signal: stores drained to L2, then bump counter ----
        asm volatile("s_waitcnt vmcnt(0)" ::: "memory");
        __syncthreads();
        if (tid == 0)
            __hip_atomic_fetch_add(ctr, 1u, __ATOMIC_RELAXED, __HIP_MEMORY_SCOPE_AGENT);
    }
}

// p = h @ Wp + bp; out = log_softmax(p). One block per batch row.
__global__ void proj_kernel(const float* __restrict__ hfin, const float* __restrict__ Wp,
                            const float* __restrict__ bp, float* __restrict__ out)
{
    const int b = blockIdx.x;
    const int tid = threadIdx.x;
    float acc[10];
#pragma unroll
    for (int c = 0; c < 10; ++c) acc[c] = 0.f;
#pragma unroll
    for (int q = 0; q < 4; ++q) {
        int k = tid + (q << 8);
        float hv = hfin[b * HD + k];
#pragma unroll
        for (int c = 0; c < 10; ++c) acc[c] += hv * Wp[k * 10 + c];
    }
#pragma unroll
    for (int off = 32; off >= 1; off >>= 1)
#pragma unroll
        for (int c = 0; c < 10; ++c) acc[c] += __shfl_down(acc[c], off);

    __shared__ float red[4][10];
    const int wv = tid >> 6, ln = tid & 63;
    if (ln == 0)
#pragma unroll
        for (int c = 0; c < 10; ++c) red[wv][c] = acc[c];
    __syncthreads();
    if (tid == 0) {
        float p[10];
#pragma unroll
        for (int c = 0; c < 10; ++c)
            p[c] = red[0][c] + red[1][c] + red[2][c] + red[3][c] + bp[c];
        float mx = p[0];
#pragma unroll
        for (int c = 1; c < 10; ++c) mx = fmaxf(mx, p[c]);
        float s = 0.f;
#pragma unroll
        for (int c = 0; c < 10; ++c) s += __expf(p[c] - mx);
        float lse = mx + logf(s);
#pragma unroll
        for (int c = 0; c < 10; ++c) out[b * 10 + c] = p[c] - lse;
    }
}

extern "C" void kernel_launch(void* const* d_in, const int* in_sizes, int n_in,
                              void* d_out, int out_size, void* d_ws, size_t ws_size,
                              hipStream_t stream) {
    const int*   x   = (const int*)d_in[0];
    const float* Wxg = (const float*)d_in[1];
    const float* Whg = (const float*)d_in[2];
    const float* bg  = (const float*)d_in[3];
    const float* Wxi = (const float*)d_in[4];
    const float* Whi = (const float*)d_in[5];
    const float* bi  = (const float*)d_in[6];
    const float* Wxf = (const float*)d_in[7];
    const float* Whf = (const float*)d_in[8];
    const float* bf_ = (const float*)d_in[9];
    const float* Wxo = (const float*)d_in[10];
    const float* Who = (const float*)d_in[11];
    const float* bo  = (const float*)d_in[12];
    const float* Wp  = (const float*)d_in[13];
    const float* bp  = (const float*)d_in[14];
    unsigned char* ws = (unsigned char*)d_ws;
    float* out = (float*)d_out;

    // zero counters/slots/flag + h_0
    hipMemsetAsync(ws, 0, 8192, stream);
    hipMemsetAsync(ws + WS_HBUF0, 0, 512 * 1024, stream);

    detect_kernel<<<16, 256, 0, stream>>>(x, (int*)(ws + WS_FLAG));
    wxb_kernel<<<160, 256, 0, stream>>>(Wxg, bg, Wxi, bi, Wxf, bf_, Wxo, bo,
                                        (float*)(ws + WS_WXB));

    const unsigned int smem_bytes = 98304;   // forces 1 block/CU (>80KB)
    hipFuncSetAttribute((const void*)lstm_main,
                        hipFuncAttributeMaxDynamicSharedMemorySize, (int)smem_bytes);

    void* args[] = { (void*)&x, (void*)&Whg, (void*)&Whi, (void*)&Whf, (void*)&Who, (void*)&ws };
    hipError_t err = hipLaunchCooperativeKernel((const void*)lstm_main, dim3(256), dim3(256),
                                                args, smem_bytes, stream);
    if (err != hipSuccess) {
        lstm_main<<<dim3(256), dim3(256), smem_bytes, stream>>>(x, Whg, Whi, Whf, Who, ws);
    }

    proj_kernel<<<256, 256, 0, stream>>>((const float*)(ws + WS_HFINAL), Wp, bp, out);
}

// Round 3
// 3342.358 us; speedup vs baseline: 8.0821x; 1.5776x over previous
//
#include <hip/hip_runtime.h>

// ============================================================================
// LSTM (B=256, S=512, H=1024, X=10, C=10) on MI355X — round 3.
// vs round 2:
//  - sync: per-block FLAG array (plain relaxed atomic stores + wave-parallel
//    atomic loads). No RMW chain (round 2's 32 serialized atomicAdds/step
//    at the far coherence point were ~8us/step).
//  - waves partition K (256 each, all 4 gates) instead of gates: A-slab read
//    once per wave-quarter -> 4x less L2 traffic; z = LDS reduction of 4
//    wave-partials.
//  - A loads: all 16 issued up front (sc0, L2-direct), consumed with counted
//    s_waitcnt vmcnt(14-2*kk) + sched_barrier(0).
//  - zbuf stride 132 (bank-conflict padding).
// ============================================================================

typedef _Float16 half8 __attribute__((ext_vector_type(8)));
typedef float f32x4 __attribute__((ext_vector_type(4)));

#define HD 1024
#define SS 512
#define ZST 132                  // zbuf row stride (floats), padded

// ws layout (bytes)
#define WS_FLAGS  0              // [8 XCDs][stride 256B]: 32 u32 step flags
#define WS_SLOT   2048           // 8 slot-claim counters
#define WS_FLAG   4096           // x dtype flag
#define WS_WXB    8192           // [4][10][1024] f32 = 163840
#define WS_HBUF0  262144         // [256][1024] f16 = 512KB
#define WS_HBUF1  786432         // [256][1024] f16 = 512KB
#define WS_HFINAL 1310720        // [256][1024] f32 = 1MB

__device__ __forceinline__ float fast_sigmoid(float x) {
    return __builtin_amdgcn_rcpf(1.f + __expf(-x));
}
__device__ __forceinline__ float fast_tanh(float x) {
    float e = __expf(-2.f * x);
    return (1.f - e) * __builtin_amdgcn_rcpf(1.f + e);
}

// x-dtype detection: if x is int64 (little endian), all odd 32-bit words are 0.
__global__ void detect_kernel(const int* __restrict__ xw, int* __restrict__ flag) {
    int i = blockIdx.x * blockDim.x + threadIdx.x;   // 0..4095
    if (xw[2 * i + 1] != 0) atomicOr(flag, 1);
}

__global__ void wxb_kernel(const float* __restrict__ Wxg, const float* __restrict__ bg,
                           const float* __restrict__ Wxi, const float* __restrict__ bi,
                           const float* __restrict__ Wxf, const float* __restrict__ bf,
                           const float* __restrict__ Wxo, const float* __restrict__ bo,
                           float* __restrict__ WxB) {
    int i = blockIdx.x * blockDim.x + threadIdx.x;   // < 40960
    if (i >= 4 * 10 * HD) return;
    int g = i / (10 * HD), r = i % (10 * HD), v = r / HD, j = r % HD;
    const float* Wx = (g == 0) ? Wxg : (g == 1) ? Wxi : (g == 2) ? Wxf : Wxo;
    const float* bb = (g == 0) ? bg  : (g == 1) ? bi  : (g == 2) ? bf  : bo;
    WxB[i] = Wx[v * HD + j] + bb[j];
}

__global__ void __launch_bounds__(256, 1)
lstm_main(const int* __restrict__ xraw, const float* __restrict__ Whg,
          const float* __restrict__ Whi, const float* __restrict__ Whf,
          const float* __restrict__ Who, unsigned char* __restrict__ ws)
{
    extern __shared__ char smem[];           // >=80KB requested: forces 1 block/CU
    float* zbuf = (float*)smem;              // [4 waves][32 rows][ZST] f32
    __shared__ int s_info;

    const int tid = threadIdx.x;
    const int w = tid >> 6, l = tid & 63;

    // ---- discover physical XCD, claim a unit-slot on it (one-time) ----
    if (tid == 0) {
        unsigned int xcc;
        asm volatile("s_getreg_b32 %0, hwreg(HW_REG_XCC_ID)" : "=s"(xcc));
        unsigned int* slotc = (unsigned int*)(ws + WS_SLOT);
        unsigned int slot = __hip_atomic_fetch_add(&slotc[xcc & 7], 1u,
                                                   __ATOMIC_RELAXED, __HIP_MEMORY_SCOPE_AGENT);
        s_info = (int)(((xcc & 7) << 8) | (slot & 31));
    }
    __syncthreads();
    const int xcd  = (s_info >> 8) & 7;
    const int slot = s_info & 31;            // 0..31 (exactly 32 blocks/XCD)

    const int row0 = xcd << 5;               // this XCD's 32 batch rows
    const int col0 = slot << 5;              // this block's 32 hidden units
    const int u  = l & 15;
    const int kg = (l >> 4) << 3;
    const int kbase = w << 8;                // wave's K-slice start (256*w)

    const int is32 = (*(const int*)(ws + WS_FLAG)) != 0;
    const float* WxB = (const float*)(ws + WS_WXB);
    _Float16* hb0 = (_Float16*)(ws + WS_HBUF0);
    _Float16* hb1 = (_Float16*)(ws + WS_HBUF1);
    float* hfinal = (float*)(ws + WS_HFINAL);
    unsigned int* flags = (unsigned int*)(ws + WS_FLAGS + xcd * 256);

    // ---- preload B fragments: wave's K-slice x (4 gates x 32 units) ----
    // bfrag[kk][nt]: k = kbase + kk*32 + (l>>4)*8 + j, z-col = nt*16 + (l&15)
    half8 bfrag[8][8];
#pragma unroll
    for (int nt = 0; nt < 8; ++nt) {
        const int g = nt >> 1;
        const float* Wmat = (g == 0) ? Whg : (g == 1) ? Whi : (g == 2) ? Whf : Who;
        const float* src = Wmat + (size_t)(kbase + kg) * HD + col0 + ((nt & 1) << 4) + u;
#pragma unroll
        for (int kk = 0; kk < 8; ++kk)
#pragma unroll
            for (int j = 0; j < 8; ++j)
                bfrag[kk][nt][j] = (_Float16)src[(size_t)(kk * 32 + j) * HD];
    }

    // c-state: thread owns (row m = p>>5, unit uu = p&31) for p = tid + 256q
    float cst[4] = {0.f, 0.f, 0.f, 0.f};

    for (int t = 0; t < SS; ++t) {
        const _Float16* hsrc = (t & 1) ? hb1 : hb0;
        _Float16*       hdst = (t & 1) ? hb0 : hb1;

        // ---- spin until all 32 blocks of this XCD published step t-1 ----
        // (wave-parallel atomic LOADS; no RMW). flags[s] == t means block s
        // finished step t-1. t=0 needs no wait (flags start at 0).
        {
            const unsigned int tgt = (unsigned int)t;
            while (1) {
                unsigned int f = __hip_atomic_load(&flags[l & 31],
                                                   __ATOMIC_RELAXED, __HIP_MEMORY_SCOPE_AGENT);
                if (__all((int)(f >= tgt))) break;
                __builtin_amdgcn_s_sleep(1);
            }
        }

        // ---- issue all 16 A loads (L1-bypass, from local-XCD L2) ----
        // areg[kk][mt]: row = row0 + (l&15) + 16*mt, k = kbase + kk*32 + kg + j
        const _Float16* aptr = hsrc + (size_t)(row0 + u) * HD + kbase + kg;
        half8 areg[8][2];
#pragma unroll
        for (int kk = 0; kk < 8; ++kk) {
#pragma unroll
            for (int mt = 0; mt < 2; ++mt)
                asm volatile("global_load_dwordx4 %0, %1, off sc0"
                             : "=v"(areg[kk][mt])
                             : "v"(aptr + (size_t)mt * 16 * HD + kk * 32));
        }

        f32x4 acc[2][8];
#pragma unroll
        for (int mt = 0; mt < 2; ++mt)
#pragma unroll
            for (int nt = 0; nt < 8; ++nt)
                acc[mt][nt] = (f32x4){0.f, 0.f, 0.f, 0.f};

#define DO_KK(KK, VM)                                                          \
        asm volatile("s_waitcnt vmcnt(" #VM ")" ::: "memory");                 \
        __builtin_amdgcn_sched_barrier(0);                                     \
        _Pragma("unroll")                                                      \
        for (int nt = 0; nt < 8; ++nt) {                                       \
            acc[0][nt] = __builtin_amdgcn_mfma_f32_16x16x32_f16(               \
                areg[KK][0], bfrag[KK][nt], acc[0][nt], 0, 0, 0);              \
            acc[1][nt] = __builtin_amdgcn_mfma_f32_16x16x32_f16(               \
                areg[KK][1], bfrag[KK][nt], acc[1][nt], 0, 0, 0);              \
        }
        DO_KK(0, 14) DO_KK(1, 12) DO_KK(2, 10) DO_KK(3, 8)
        DO_KK(4, 6)  DO_KK(5, 4)  DO_KK(6, 2)  DO_KK(7, 0)
#undef DO_KK

        // ---- write wave-partial z to LDS ----
        // D layout (verified r1/r2): row = mt*16 + (l>>4)*4 + rr, col = nt*16 + u
#pragma unroll
        for (int mt = 0; mt < 2; ++mt)
#pragma unroll
            for (int nt = 0; nt < 8; ++nt)
#pragma unroll
                for (int rr = 0; rr < 4; ++rr)
                    zbuf[(size_t)(w * 32 + mt * 16 + ((l >> 4) << 2) + rr) * ZST
                         + nt * 16 + u] = acc[mt][nt][rr];
        __syncthreads();

        // ---- gates: z = sum of 4 wave partials + WxB[xt]; c/h update ----
        const int lastt = (t == SS - 1);
#pragma unroll
        for (int q = 0; q < 4; ++q) {
            const int p = tid + (q << 8);
            const int m = p >> 5, uu = p & 31;
            const int brow = row0 + m;
            const size_t xi = (size_t)brow * SS + t;
            const int xv = is32 ? xraw[xi] : xraw[xi << 1];   // int64: low word
            const int j = col0 + uu;
            float zg = WxB[(size_t)xv * HD + j];
            float zi = WxB[(size_t)(10 + xv) * HD + j];
            float zf = WxB[(size_t)(20 + xv) * HD + j];
            float zo = WxB[(size_t)(30 + xv) * HD + j];
#pragma unroll
            for (int wv = 0; wv < 4; ++wv) {
                const float* zr = zbuf + (size_t)(wv * 32 + m) * ZST;
                zg += zr[uu];
                zi += zr[32 + uu];
                zf += zr[64 + uu];
                zo += zr[96 + uu];
            }
            float gg = fast_tanh(zg);
            float ii = fast_sigmoid(zi);
            float ff = fast_sigmoid(zf);
            float oo = fast_sigmoid(zo);
            float cv = gg * ii + cst[q] * ff;
            cst[q] = cv;
            float hv = fast_tanh(cv) * oo;
            hdst[(size_t)brow * HD + j] = (_Float16)hv;
            if (lastt) hfinal[(size_t)brow * HD + j] = hv;
        }

        // ---- publish: h stores drained to L2, then parallel flag store ----
        asm volatile("s_waitcnt vmcnt(0)" ::: "memory");
        __syncthreads();
        if (tid == 0)
            __hip_atomic_store(&flags[slot], (unsigned int)(t + 1),
                               __ATOMIC_RELAXED, __HIP_MEMORY_SCOPE_AGENT);
    }
}

// p = h @ Wp + bp; out = log_softmax(p). One block per batch row.
__global__ void proj_kernel(const float* __restrict__ hfin, const float* __restrict__ Wp,
                            const float* __restrict__ bp, float* __restrict__ out)
{
    const int b = blockIdx.x;
    const int tid = threadIdx.x;
    float acc[10];
#pragma unroll
    for (int c = 0; c < 10; ++c) acc[c] = 0.f;
#pragma unroll
    for (int q = 0; q < 4; ++q) {
        int k = tid + (q << 8);
        float hv = hfin[b * HD + k];
#pragma unroll
        for (int c = 0; c < 10; ++c) acc[c] += hv * Wp[k * 10 + c];
    }
#pragma unroll
    for (int off = 32; off >= 1; off >>= 1)
#pragma unroll
        for (int c = 0; c < 10; ++c) acc[c] += __shfl_down(acc[c], off);

    __shared__ float red[4][10];
    const int wv = tid >> 6, ln = tid & 63;
    if (ln == 0)
#pragma unroll
        for (int c = 0; c < 10; ++c) red[wv][c] = acc[c];
    __syncthreads();
    if (tid == 0) {
        float p[10];
#pragma unroll
        for (int c = 0; c < 10; ++c)
            p[c] = red[0][c] + red[1][c] + red[2][c] + red[3][c] + bp[c];
        float mx = p[0];
#pragma unroll
        for (int c = 1; c < 10; ++c) mx = fmaxf(mx, p[c]);
        float s = 0.f;
#pragma unroll
        for (int c = 0; c < 10; ++c) s += __expf(p[c] - mx);
        float lse = mx + logf(s);
#pragma unroll
        for (int c = 0; c < 10; ++c) out[b * 10 + c] = p[c] - lse;
    }
}

extern "C" void kernel_launch(void* const* d_in, const int* in_sizes, int n_in,
                              void* d_out, int out_size, void* d_ws, size_t ws_size,
                              hipStream_t stream) {
    const int*   x   = (const int*)d_in[0];
    const float* Wxg = (const float*)d_in[1];
    const float* Whg = (const float*)d_in[2];
    const float* bg  = (const float*)d_in[3];
    const float* Wxi = (const float*)d_in[4];
    const float* Whi = (const float*)d_in[5];
    const float* bi  = (const float*)d_in[6];
    const float* Wxf = (const float*)d_in[7];
    const float* Whf = (const float*)d_in[8];
    const float* bf_ = (const float*)d_in[9];
    const float* Wxo = (const float*)d_in[10];
    const float* Who = (const float*)d_in[11];
    const float* bo  = (const float*)d_in[12];
    const float* Wp  = (const float*)d_in[13];
    const float* bp  = (const float*)d_in[14];
    unsigned char* ws = (unsigned char*)d_ws;
    float* out = (float*)d_out;

    // zero flags/slots/dtype-flag + h_0
    hipMemsetAsync(ws, 0, 8192, stream);
    hipMemsetAsync(ws + WS_HBUF0, 0, 512 * 1024, stream);

    detect_kernel<<<16, 256, 0, stream>>>(x, (int*)(ws + WS_FLAG));
    wxb_kernel<<<160, 256, 0, stream>>>(Wxg, bg, Wxi, bi, Wxf, bf_, Wxo, bo,
                                        (float*)(ws + WS_WXB));

    const unsigned int smem_bytes = 98304;   // forces 1 block/CU (pigeonhole: 32/XCD)
    hipFuncSetAttribute((const void*)lstm_main,
                        hipFuncAttributeMaxDynamicSharedMemorySize, (int)smem_bytes);

    void* args[] = { (void*)&x, (void*)&Whg, (void*)&Whi, (void*)&Whf, (void*)&Who, (void*)&ws };
    hipError_t err = hipLaunchCooperativeKernel((const void*)lstm_main, dim3(256), dim3(256),
                                                args, smem_bytes, stream);
    if (err != hipSuccess) {
        lstm_main<<<dim3(256), dim3(256), smem_bytes, stream>>>(x, Whg, Whi, Whf, Who, ws);
    }

    proj_kernel<<<256, 256, 0, stream>>>((const float*)(ws + WS_HFINAL), Wp, bp, out);
}

// Round 4
// 2984.182 us; speedup vs baseline: 9.0522x; 1.1200x over previous
//
#include <hip/hip_runtime.h>

// ============================================================================
// LSTM (B=256, S=512, H=1024, X=10, C=10) on MI355X — round 4.
// vs round 3 (same partitioning / MFMA layout / sync protocol):
//  - WxB + x prefetched BEFORE the spin (independent of h)
//  - only wave 0 polls the flag line; others wait at __syncthreads
//  - z-exchange transposed: zT[wv][col][row(36)] -> f32x4 ds_write_b128
//    (rr contiguous), gate reads stride-36 conflict-free (unit pair u, u+16)
//  - gate phase: 2 slots x 2 units per thread
// ============================================================================

typedef _Float16 half8 __attribute__((ext_vector_type(8)));
typedef float f32x4 __attribute__((ext_vector_type(4)));

#define HD 1024
#define SS 512
#define ROWP 36                  // padded row stride (floats), 16B-aligned
#define COLS 128                 // z-cols per block (4 gates x 32 units)

// ws layout (bytes)
#define WS_FLAGS  0              // [8 XCDs][stride 256B]: 32 u32 step flags
#define WS_SLOT   2048           // 8 slot-claim counters
#define WS_FLAG   4096           // x dtype flag
#define WS_WXB    8192           // [4][10][1024] f32 = 163840
#define WS_HBUF0  262144         // [256][1024] f16 = 512KB
#define WS_HBUF1  786432         // [256][1024] f16 = 512KB
#define WS_HFINAL 1310720        // [256][1024] f32 = 1MB

__device__ __forceinline__ float fast_sigmoid(float x) {
    return __builtin_amdgcn_rcpf(1.f + __expf(-x));
}
__device__ __forceinline__ float fast_tanh(float x) {
    float e = __expf(-2.f * x);
    return (1.f - e) * __builtin_amdgcn_rcpf(1.f + e);
}

// x-dtype detection: if x is int64 (little endian), all odd 32-bit words are 0.
__global__ void detect_kernel(const int* __restrict__ xw, int* __restrict__ flag) {
    int i = blockIdx.x * blockDim.x + threadIdx.x;   // 0..4095
    if (xw[2 * i + 1] != 0) atomicOr(flag, 1);
}

__global__ void wxb_kernel(const float* __restrict__ Wxg, const float* __restrict__ bg,
                           const float* __restrict__ Wxi, const float* __restrict__ bi,
                           const float* __restrict__ Wxf, const float* __restrict__ bf,
                           const float* __restrict__ Wxo, const float* __restrict__ bo,
                           float* __restrict__ WxB) {
    int i = blockIdx.x * blockDim.x + threadIdx.x;   // < 40960
    if (i >= 4 * 10 * HD) return;
    int g = i / (10 * HD), r = i % (10 * HD), v = r / HD, j = r % HD;
    const float* Wx = (g == 0) ? Wxg : (g == 1) ? Wxi : (g == 2) ? Wxf : Wxo;
    const float* bb = (g == 0) ? bg  : (g == 1) ? bi  : (g == 2) ? bf  : bo;
    WxB[i] = Wx[v * HD + j] + bb[j];
}

__global__ void __launch_bounds__(256, 1)
lstm_main(const int* __restrict__ xraw, const float* __restrict__ Whg,
          const float* __restrict__ Whi, const float* __restrict__ Whf,
          const float* __restrict__ Who, unsigned char* __restrict__ ws)
{
    extern __shared__ char smem[];           // 96KB requested: forces 1 block/CU
    float* zT = (float*)smem;                // [4 wv][128 col][ROWP] f32 = 72KB
    __shared__ int s_info;

    const int tid = threadIdx.x;
    const int w = tid >> 6, l = tid & 63;

    // ---- discover physical XCD, claim a unit-slot on it (one-time) ----
    if (tid == 0) {
        unsigned int xcc;
        asm volatile("s_getreg_b32 %0, hwreg(HW_REG_XCC_ID)" : "=s"(xcc));
        unsigned int* slotc = (unsigned int*)(ws + WS_SLOT);
        unsigned int slot = __hip_atomic_fetch_add(&slotc[xcc & 7], 1u,
                                                   __ATOMIC_RELAXED, __HIP_MEMORY_SCOPE_AGENT);
        s_info = (int)(((xcc & 7) << 8) | (slot & 31));
    }
    __syncthreads();
    const int xcd  = (s_info >> 8) & 7;
    const int slot = s_info & 31;            // 0..31 (exactly 32 blocks/XCD)

    const int row0 = xcd << 5;               // this XCD's 32 batch rows
    const int col0 = slot << 5;              // this block's 32 hidden units
    const int u  = l & 15;
    const int kg = (l >> 4) << 3;
    const int kbase = w << 8;                // wave's K-slice start (256*w)

    const int is32 = (*(const int*)(ws + WS_FLAG)) != 0;
    const float* WxB = (const float*)(ws + WS_WXB);
    _Float16* hb0 = (_Float16*)(ws + WS_HBUF0);
    _Float16* hb1 = (_Float16*)(ws + WS_HBUF1);
    float* hfinal = (float*)(ws + WS_HFINAL);
    unsigned int* flags = (unsigned int*)(ws + WS_FLAGS + xcd * 256);

    // ---- preload B fragments: wave's K-slice x (4 gates x 32 units) ----
    // bfrag[kk][nt]: k = kbase + kk*32 + (l>>4)*8 + j, z-col = nt*16 + (l&15)
    half8 bfrag[8][8];
#pragma unroll
    for (int nt = 0; nt < 8; ++nt) {
        const int g = nt >> 1;
        const float* Wmat = (g == 0) ? Whg : (g == 1) ? Whi : (g == 2) ? Whf : Who;
        const float* src = Wmat + (size_t)(kbase + kg) * HD + col0 + ((nt & 1) << 4) + u;
#pragma unroll
        for (int kk = 0; kk < 8; ++kk)
#pragma unroll
            for (int j = 0; j < 8; ++j)
                bfrag[kk][nt][j] = (_Float16)src[(size_t)(kk * 32 + j) * HD];
    }

    // gate-phase ownership: slot q in {0,1}: sl = tid + 256q,
    //   m = sl>>4 (row 0..31), pr = sl&15, units {pr, pr+16}
    const int gm0 = tid >> 4;                // q=0 row
    const int gm1 = (tid + 256) >> 4;        // q=1 row
    const int gpr = tid & 15;
    float cst[2][2] = {{0.f, 0.f}, {0.f, 0.f}};

    for (int t = 0; t < SS; ++t) {
        const _Float16* hsrc = (t & 1) ? hb1 : hb0;
        _Float16*       hdst = (t & 1) ? hb0 : hb1;

        // ---- prefetch x + WxB for THIS step (independent of h) ----
        float wx[2][2][4];                   // [q][u_i][gate]
#pragma unroll
        for (int q = 0; q < 2; ++q) {
            const int m = q ? gm1 : gm0;
            const size_t xi = (size_t)(row0 + m) * SS + t;
            const int xv = is32 ? xraw[xi] : xraw[xi << 1];   // int64: low word
#pragma unroll
            for (int ui = 0; ui < 2; ++ui) {
                const int j = col0 + gpr + (ui << 4);
#pragma unroll
                for (int g = 0; g < 4; ++g)
                    wx[q][ui][g] = WxB[(size_t)(g * 10 + xv) * HD + j];
            }
        }
        __builtin_amdgcn_sched_barrier(0);   // pin prefetch issue before spin

        // ---- wave 0 polls; everyone else parks at the barrier ----
        if (w == 0) {
            const unsigned int tgt = (unsigned int)t;
            while (1) {
                unsigned int f = __hip_atomic_load(&flags[l & 31],
                                                   __ATOMIC_RELAXED, __HIP_MEMORY_SCOPE_AGENT);
                if (__all((int)(f >= tgt))) break;
            }
        }
        __syncthreads();

        // ---- issue all 16 A loads (L1-bypass, from local-XCD L2) ----
        const _Float16* aptr = hsrc + (size_t)(row0 + u) * HD + kbase + kg;
        half8 areg[8][2];
#pragma unroll
        for (int kk = 0; kk < 8; ++kk) {
#pragma unroll
            for (int mt = 0; mt < 2; ++mt)
                asm volatile("global_load_dwordx4 %0, %1, off sc0"
                             : "=v"(areg[kk][mt])
                             : "v"(aptr + (size_t)mt * 16 * HD + kk * 32));
        }

        f32x4 acc[2][8];
#pragma unroll
        for (int mt = 0; mt < 2; ++mt)
#pragma unroll
            for (int nt = 0; nt < 8; ++nt)
                acc[mt][nt] = (f32x4){0.f, 0.f, 0.f, 0.f};

        // vmcnt(N) semantics: waits until <=N outstanding; older prefetch
        // loads drain first, so 14-2kk still guarantees A pair kk is ready.
#define DO_KK(KK, VM)                                                          \
        asm volatile("s_waitcnt vmcnt(" #VM ")" ::: "memory");                 \
        __builtin_amdgcn_sched_barrier(0);                                     \
        _Pragma("unroll")                                                      \
        for (int nt = 0; nt < 8; ++nt) {                                       \
            acc[0][nt] = __builtin_amdgcn_mfma_f32_16x16x32_f16(               \
                areg[KK][0], bfrag[KK][nt], acc[0][nt], 0, 0, 0);              \
            acc[1][nt] = __builtin_amdgcn_mfma_f32_16x16x32_f16(               \
                areg[KK][1], bfrag[KK][nt], acc[1][nt], 0, 0, 0);              \
        }
        DO_KK(0, 14) DO_KK(1, 12) DO_KK(2, 10) DO_KK(3, 8)
        DO_KK(4, 6)  DO_KK(5, 4)  DO_KK(6, 2)  DO_KK(7, 0)
#undef DO_KK

        // ---- write wave-partial z to LDS (vectorized, rr contiguous) ----
        // D layout: row = mt*16 + (l>>4)*4 + rr, col = nt*16 + u
#pragma unroll
        for (int mt = 0; mt < 2; ++mt)
#pragma unroll
            for (int nt = 0; nt < 8; ++nt) {
                const int col = nt * 16 + u;
                const int rowb = mt * 16 + ((l >> 4) << 2);
                *(f32x4*)&zT[(size_t)w * COLS * ROWP + col * ROWP + rowb] = acc[mt][nt];
            }
        __syncthreads();

        // ---- gates: z = sum of 4 wave partials + prefetched WxB ----
        const int lastt = (t == SS - 1);
#pragma unroll
        for (int q = 0; q < 2; ++q) {
            const int m = q ? gm1 : gm0;
            const int brow = row0 + m;
#pragma unroll
            for (int ui = 0; ui < 2; ++ui) {
                const int uu = gpr + (ui << 4);
                const int j = col0 + uu;
                float zv[4];
#pragma unroll
                for (int g = 0; g < 4; ++g) {
                    float s = wx[q][ui][g];
                    const int cb = (g * 32 + uu) * ROWP + m;
#pragma unroll
                    for (int wv = 0; wv < 4; ++wv)
                        s += zT[wv * COLS * ROWP + cb];
                    zv[g] = s;
                }
                float gg = fast_tanh(zv[0]);
                float ii = fast_sigmoid(zv[1]);
                float ff = fast_sigmoid(zv[2]);
                float oo = fast_sigmoid(zv[3]);
                float cv = gg * ii + cst[q][ui] * ff;
                cst[q][ui] = cv;
                float hv = fast_tanh(cv) * oo;
                hdst[(size_t)brow * HD + j] = (_Float16)hv;
                if (lastt) hfinal[(size_t)brow * HD + j] = hv;
            }
        }

        // ---- publish: h stores drained to L2, then parallel flag store ----
        asm volatile("s_waitcnt vmcnt(0)" ::: "memory");
        __syncthreads();
        if (tid == 0)
            __hip_atomic_store(&flags[slot], (unsigned int)(t + 1),
                               __ATOMIC_RELAXED, __HIP_MEMORY_SCOPE_AGENT);
    }
}

// p = h @ Wp + bp; out = log_softmax(p). One block per batch row.
__global__ void proj_kernel(const float* __restrict__ hfin, const float* __restrict__ Wp,
                            const float* __restrict__ bp, float* __restrict__ out)
{
    const int b = blockIdx.x;
    const int tid = threadIdx.x;
    float acc[10];
#pragma unroll
    for (int c = 0; c < 10; ++c) acc[c] = 0.f;
#pragma unroll
    for (int q = 0; q < 4; ++q) {
        int k = tid + (q << 8);
        float hv = hfin[b * HD + k];
#pragma unroll
        for (int c = 0; c < 10; ++c) acc[c] += hv * Wp[k * 10 + c];
    }
#pragma unroll
    for (int off = 32; off >= 1; off >>= 1)
#pragma unroll
        for (int c = 0; c < 10; ++c) acc[c] += __shfl_down(acc[c], off);

    __shared__ float red[4][10];
    const int wv = tid >> 6, ln = tid & 63;
    if (ln == 0)
#pragma unroll
        for (int c = 0; c < 10; ++c) red[wv][c] = acc[c];
    __syncthreads();
    if (tid == 0) {
        float p[10];
#pragma unroll
        for (int c = 0; c < 10; ++c)
            p[c] = red[0][c] + red[1][c] + red[2][c] + red[3][c] + bp[c];
        float mx = p[0];
#pragma unroll
        for (int c = 1; c < 10; ++c) mx = fmaxf(mx, p[c]);
        float s = 0.f;
#pragma unroll
        for (int c = 0; c < 10; ++c) s += __expf(p[c] - mx);
        float lse = mx + logf(s);
#pragma unroll
        for (int c = 0; c < 10; ++c) out[b * 10 + c] = p[c] - lse;
    }
}

extern "C" void kernel_launch(void* const* d_in, const int* in_sizes, int n_in,
                              void* d_out, int out_size, void* d_ws, size_t ws_size,
                              hipStream_t stream) {
    const int*   x   = (const int*)d_in[0];
    const float* Wxg = (const float*)d_in[1];
    const float* Whg = (const float*)d_in[2];
    const float* bg  = (const float*)d_in[3];
    const float* Wxi = (const float*)d_in[4];
    const float* Whi = (const float*)d_in[5];
    const float* bi  = (const float*)d_in[6];
    const float* Wxf = (const float*)d_in[7];
    const float* Whf = (const float*)d_in[8];
    const float* bf_ = (const float*)d_in[9];
    const float* Wxo = (const float*)d_in[10];
    const float* Who = (const float*)d_in[11];
    const float* bo  = (const float*)d_in[12];
    const float* Wp  = (const float*)d_in[13];
    const float* bp  = (const float*)d_in[14];
    unsigned char* ws = (unsigned char*)d_ws;
    float* out = (float*)d_out;

    // zero flags/slots/dtype-flag + h_0
    hipMemsetAsync(ws, 0, 8192, stream);
    hipMemsetAsync(ws + WS_HBUF0, 0, 512 * 1024, stream);

    detect_kernel<<<16, 256, 0, stream>>>(x, (int*)(ws + WS_FLAG));
    wxb_kernel<<<160, 256, 0, stream>>>(Wxg, bg, Wxi, bi, Wxf, bf_, Wxo, bo,
                                        (float*)(ws + WS_WXB));

    const unsigned int smem_bytes = 98304;   // forces 1 block/CU (pigeonhole: 32/XCD)
    hipFuncSetAttribute((const void*)lstm_main,
                        hipFuncAttributeMaxDynamicSharedMemorySize, (int)smem_bytes);

    void* args[] = { (void*)&x, (void*)&Whg, (void*)&Whi, (void*)&Whf, (void*)&Who, (void*)&ws };
    hipError_t err = hipLaunchCooperativeKernel((const void*)lstm_main, dim3(256), dim3(256),
                                                args, smem_bytes, stream);
    if (err != hipSuccess) {
        lstm_main<<<dim3(256), dim3(256), smem_bytes, stream>>>(x, Whg, Whi, Whf, Who, ws);
    }

    proj_kernel<<<256, 256, 0, stream>>>((const float*)(ws + WS_HFINAL), Wp, bp, out);
}

// Round 6
// 2749.915 us; speedup vs baseline: 9.8233x; 1.0852x over previous
//
#include <hip/hip_runtime.h>

// ============================================================================
// LSTM (B=256, S=512, H=1024, X=10, C=10) on MI355X — round 6 (= round 5
// resubmitted; previous bench was an infra failure, not a kernel verdict).
//  - chunk-granular dataflow sync: wave w's chunk kk needs ONLY producer
//    slot 8w+kk's flag (not all 32). Half-split schedule: poll 4 / issue 8
//    loads / poll 4 / issue 8 / MFMA x8 with counted vmcnt. Waiting for late
//    producers overlaps with loads+MFMA of ready chunks.
//    (Double-buffer safety invariant: h(t) store happens after all 4 waves'
//    polls collectively confirmed all 32 flags >= t, joined by barrier.)
//  - z-exchange: round 3's exact scalar layout (measured 0 bank conflicts).
//  - wx/x prefetch before polls (poll's implicit vmcnt(0) drains it free).
// ============================================================================

typedef _Float16 half8 __attribute__((ext_vector_type(8)));
typedef float f32x4 __attribute__((ext_vector_type(4)));

#define HD 1024
#define SS 512
#define ZST 132                  // z row stride (floats), r3-proven

// ws layout (bytes)
#define WS_FLAGS  0              // [8 XCDs][stride 256B]: 32 u32 step flags
#define WS_SLOT   2048           // 8 slot-claim counters
#define WS_FLAG   4096           // x dtype flag
#define WS_WXB    8192           // [4][10][1024] f32 = 163840
#define WS_HBUF0  262144         // [256][1024] f16 = 512KB
#define WS_HBUF1  786432         // [256][1024] f16 = 512KB
#define WS_HFINAL 1310720        // [256][1024] f32 = 1MB

__device__ __forceinline__ float fast_sigmoid(float x) {
    return __builtin_amdgcn_rcpf(1.f + __expf(-x));
}
__device__ __forceinline__ float fast_tanh(float x) {
    float e = __expf(-2.f * x);
    return (1.f - e) * __builtin_amdgcn_rcpf(1.f + e);
}

// x-dtype detection: if x is int64 (little endian), all odd 32-bit words are 0.
__global__ void detect_kernel(const int* __restrict__ xw, int* __restrict__ flag) {
    int i = blockIdx.x * blockDim.x + threadIdx.x;   // 0..4095
    if (xw[2 * i + 1] != 0) atomicOr(flag, 1);
}

__global__ void wxb_kernel(const float* __restrict__ Wxg, const float* __restrict__ bg,
                           const float* __restrict__ Wxi, const float* __restrict__ bi,
                           const float* __restrict__ Wxf, const float* __restrict__ bf,
                           const float* __restrict__ Wxo, const float* __restrict__ bo,
                           float* __restrict__ WxB) {
    int i = blockIdx.x * blockDim.x + threadIdx.x;   // < 40960
    if (i >= 4 * 10 * HD) return;
    int g = i / (10 * HD), r = i % (10 * HD), v = r / HD, j = r % HD;
    const float* Wx = (g == 0) ? Wxg : (g == 1) ? Wxi : (g == 2) ? Wxf : Wxo;
    const float* bb = (g == 0) ? bg  : (g == 1) ? bi  : (g == 2) ? bf  : bo;
    WxB[i] = Wx[v * HD + j] + bb[j];
}

__global__ void __launch_bounds__(256, 1)
lstm_main(const int* __restrict__ xraw, const float* __restrict__ Whg,
          const float* __restrict__ Whi, const float* __restrict__ Whf,
          const float* __restrict__ Who, unsigned char* __restrict__ ws)
{
    extern __shared__ char smem[];           // 96KB requested: forces 1 block/CU
    float* zbuf = (float*)smem;              // [4 wv * 32 rows][ZST] f32 (r3 layout)
    __shared__ int s_info;

    const int tid = threadIdx.x;
    const int w = tid >> 6, l = tid & 63;

    // ---- discover physical XCD, claim a unit-slot on it (one-time) ----
    if (tid == 0) {
        unsigned int xcc;
        asm volatile("s_getreg_b32 %0, hwreg(HW_REG_XCC_ID)" : "=s"(xcc));
        unsigned int* slotc = (unsigned int*)(ws + WS_SLOT);
        unsigned int slot = __hip_atomic_fetch_add(&slotc[xcc & 7], 1u,
                                                   __ATOMIC_RELAXED, __HIP_MEMORY_SCOPE_AGENT);
        s_info = (int)(((xcc & 7) << 8) | (slot & 31));
    }
    __syncthreads();
    const int xcd  = (s_info >> 8) & 7;
    const int slot = s_info & 31;            // 0..31 (exactly 32 blocks/XCD)

    const int row0 = xcd << 5;               // this XCD's 32 batch rows
    const int col0 = slot << 5;              // this block's 32 hidden units
    const int u  = l & 15;
    const int kg = (l >> 4) << 3;
    const int kbase = w << 8;                // wave's K-slice start (256*w)

    const int is32 = (*(const int*)(ws + WS_FLAG)) != 0;
    const float* WxB = (const float*)(ws + WS_WXB);
    _Float16* hb0 = (_Float16*)(ws + WS_HBUF0);
    _Float16* hb1 = (_Float16*)(ws + WS_HBUF1);
    float* hfinal = (float*)(ws + WS_HFINAL);
    unsigned int* flags = (unsigned int*)(ws + WS_FLAGS + xcd * 256);

    // ---- preload B fragments: wave's K-slice x (4 gates x 32 units) ----
    // bfrag[kk][nt]: k = kbase + kk*32 + (l>>4)*8 + j, z-col = nt*16 + (l&15)
    half8 bfrag[8][8];
#pragma unroll
    for (int nt = 0; nt < 8; ++nt) {
        const int g = nt >> 1;
        const float* Wmat = (g == 0) ? Whg : (g == 1) ? Whi : (g == 2) ? Whf : Who;
        const float* src = Wmat + (size_t)(kbase + kg) * HD + col0 + ((nt & 1) << 4) + u;
#pragma unroll
        for (int kk = 0; kk < 8; ++kk)
#pragma unroll
            for (int j = 0; j < 8; ++j)
                bfrag[kk][nt][j] = (_Float16)src[(size_t)(kk * 32 + j) * HD];
    }

    // c-state: thread owns (row m = p>>5, unit uu = p&31) for p = tid + 256q
    float cst[4] = {0.f, 0.f, 0.f, 0.f};

    // chunk kk of wave w is produced by block slot 8w+kk
    const unsigned int* myflag0 = &flags[(w << 3) + (l & 3)];       // chunks 0..3
    const unsigned int* myflag1 = &flags[(w << 3) + 4 + (l & 3)];   // chunks 4..7

    for (int t = 0; t < SS; ++t) {
        const _Float16* hsrc = (t & 1) ? hb1 : hb0;
        _Float16*       hdst = (t & 1) ? hb0 : hb1;
        const unsigned int tgt = (unsigned int)t;

        // ---- prefetch x + WxB for THIS step (independent of h) ----
        float wx[4][4];                      // [q][gate]
#pragma unroll
        for (int q = 0; q < 4; ++q) {
            const int p = tid + (q << 8);
            const int m = p >> 5, uu = p & 31;
            const size_t xi = (size_t)(row0 + m) * SS + t;
            const int xv = is32 ? xraw[xi] : xraw[xi << 1];   // int64: low word
            const int j = col0 + uu;
#pragma unroll
            for (int g = 0; g < 4; ++g)
                wx[q][g] = WxB[(size_t)(g * 10 + xv) * HD + j];
        }
        __builtin_amdgcn_sched_barrier(0);

        const _Float16* aptr = hsrc + (size_t)(row0 + u) * HD + kbase + kg;
        half8 areg[8][2];

        // ---- poll producers of chunks 0..3 (lanes parallel; drains wx) ----
        while (1) {
            unsigned int f = __hip_atomic_load(myflag0, __ATOMIC_RELAXED,
                                               __HIP_MEMORY_SCOPE_AGENT);
            if (__all((int)(f >= tgt))) break;
        }
        __builtin_amdgcn_sched_barrier(0);
        // ---- issue chunks 0..3 (8 loads) ----
#pragma unroll
        for (int kk = 0; kk < 4; ++kk)
#pragma unroll
            for (int mt = 0; mt < 2; ++mt)
                asm volatile("global_load_dwordx4 %0, %1, off sc0"
                             : "=v"(areg[kk][mt])
                             : "v"(aptr + (size_t)mt * 16 * HD + kk * 32));
        // ---- poll producers of chunks 4..7 (implicit vmcnt(0) drains 0..3) ----
        while (1) {
            unsigned int f = __hip_atomic_load(myflag1, __ATOMIC_RELAXED,
                                               __HIP_MEMORY_SCOPE_AGENT);
            if (__all((int)(f >= tgt))) break;
        }
        __builtin_amdgcn_sched_barrier(0);
        // ---- issue chunks 4..7 ----
#pragma unroll
        for (int kk = 4; kk < 8; ++kk)
#pragma unroll
            for (int mt = 0; mt < 2; ++mt)
                asm volatile("global_load_dwordx4 %0, %1, off sc0"
                             : "=v"(areg[kk][mt])
                             : "v"(aptr + (size_t)mt * 16 * HD + kk * 32));

        f32x4 acc[2][8];
#pragma unroll
        for (int mt = 0; mt < 2; ++mt)
#pragma unroll
            for (int nt = 0; nt < 8; ++nt)
                acc[mt][nt] = (f32x4){0.f, 0.f, 0.f, 0.f};

        // chunks 0..3 data already drained by second poll; 4..7 counted.
#define DO_KK(KK, VM)                                                          \
        asm volatile("s_waitcnt vmcnt(" #VM ")" ::: "memory");                 \
        __builtin_amdgcn_sched_barrier(0);                                     \
        _Pragma("unroll")                                                      \
        for (int nt = 0; nt < 8; ++nt) {                                       \
            acc[0][nt] = __builtin_amdgcn_mfma_f32_16x16x32_f16(               \
                areg[KK][0], bfrag[KK][nt], acc[0][nt], 0, 0, 0);              \
            acc[1][nt] = __builtin_amdgcn_mfma_f32_16x16x32_f16(               \
                areg[KK][1], bfrag[KK][nt], acc[1][nt], 0, 0, 0);              \
        }
        DO_KK(0, 8) DO_KK(1, 8) DO_KK(2, 8) DO_KK(3, 8)
        DO_KK(4, 6) DO_KK(5, 4) DO_KK(6, 2) DO_KK(7, 0)
#undef DO_KK

        // ---- write wave-partial z to LDS (r3 scalar layout, 0 conflicts) ----
        // D layout: row = mt*16 + (l>>4)*4 + rr, col = nt*16 + u
#pragma unroll
        for (int mt = 0; mt < 2; ++mt)
#pragma unroll
            for (int nt = 0; nt < 8; ++nt)
#pragma unroll
                for (int rr = 0; rr < 4; ++rr)
                    zbuf[(size_t)(w * 32 + mt * 16 + ((l >> 4) << 2) + rr) * ZST
                         + nt * 16 + u] = acc[mt][nt][rr];
        __syncthreads();

        // ---- gates: z = sum of 4 wave partials + prefetched WxB ----
        const int lastt = (t == SS - 1);
#pragma unroll
        for (int q = 0; q < 4; ++q) {
            const int p = tid + (q << 8);
            const int m = p >> 5, uu = p & 31;
            const int brow = row0 + m;
            const int j = col0 + uu;
            float zg = wx[q][0], zi = wx[q][1], zf = wx[q][2], zo = wx[q][3];
#pragma unroll
            for (int wv = 0; wv < 4; ++wv) {
                const float* zr = zbuf + (size_t)(wv * 32 + m) * ZST;
                zg += zr[uu];
                zi += zr[32 + uu];
                zf += zr[64 + uu];
                zo += zr[96 + uu];
            }
            float gg = fast_tanh(zg);
            float ii = fast_sigmoid(zi);
            float ff = fast_sigmoid(zf);
            float oo = fast_sigmoid(zo);
            float cv = gg * ii + cst[q] * ff;
            cst[q] = cv;
            float hv = fast_tanh(cv) * oo;
            hdst[(size_t)brow * HD + j] = (_Float16)hv;
            if (lastt) hfinal[(size_t)brow * HD + j] = hv;
        }

        // ---- publish: h stores drained to L2, then flag store ----
        asm volatile("s_waitcnt vmcnt(0)" ::: "memory");
        __syncthreads();
        if (tid == 0)
            __hip_atomic_store(&flags[slot], (unsigned int)(t + 1),
                               __ATOMIC_RELAXED, __HIP_MEMORY_SCOPE_AGENT);
    }
}

// p = h @ Wp + bp; out = log_softmax(p). One block per batch row.
__global__ void proj_kernel(const float* __restrict__ hfin, const float* __restrict__ Wp,
                            const float* __restrict__ bp, float* __restrict__ out)
{
    const int b = blockIdx.x;
    const int tid = threadIdx.x;
    float acc[10];
#pragma unroll
    for (int c = 0; c < 10; ++c) acc[c] = 0.f;
#pragma unroll
    for (int q = 0; q < 4; ++q) {
        int k = tid + (q << 8);
        float hv = hfin[b * HD + k];
#pragma unroll
        for (int c = 0; c < 10; ++c) acc[c] += hv * Wp[k * 10 + c];
    }
#pragma unroll
    for (int off = 32; off >= 1; off >>= 1)
#pragma unroll
        for (int c = 0; c < 10; ++c) acc[c] += __shfl_down(acc[c], off);

    __shared__ float red[4][10];
    const int wv = tid >> 6, ln = tid & 63;
    if (ln == 0)
#pragma unroll
        for (int c = 0; c < 10; ++c) red[wv][c] = acc[c];
    __syncthreads();
    if (tid == 0) {
        float p[10];
#pragma unroll
        for (int c = 0; c < 10; ++c)
            p[c] = red[0][c] + red[1][c] + red[2][c] + red[3][c] + bp[c];
        float mx = p[0];
#pragma unroll
        for (int c = 1; c < 10; ++c) mx = fmaxf(mx, p[c]);
        float s = 0.f;
#pragma unroll
        for (int c = 0; c < 10; ++c) s += __expf(p[c] - mx);
        float lse = mx + logf(s);
#pragma unroll
        for (int c = 0; c < 10; ++c) out[b * 10 + c] = p[c] - lse;
    }
}

extern "C" void kernel_launch(void* const* d_in, const int* in_sizes, int n_in,
                              void* d_out, int out_size, void* d_ws, size_t ws_size,
                              hipStream_t stream) {
    const int*   x   = (const int*)d_in[0];
    const float* Wxg = (const float*)d_in[1];
    const float* Whg = (const float*)d_in[2];
    const float* bg  = (const float*)d_in[3];
    const float* Wxi = (const float*)d_in[4];
    const float* Whi = (const float*)d_in[5];
    const float* bi  = (const float*)d_in[6];
    const float* Wxf = (const float*)d_in[7];
    const float* Whf = (const float*)d_in[8];
    const float* bf_ = (const float*)d_in[9];
    const float* Wxo = (const float*)d_in[10];
    const float* Who = (const float*)d_in[11];
    const float* bo  = (const float*)d_in[12];
    const float* Wp  = (const float*)d_in[13];
    const float* bp  = (const float*)d_in[14];
    unsigned char* ws = (unsigned char*)d_ws;
    float* out = (float*)d_out;

    // zero flags/slots/dtype-flag + h_0
    hipMemsetAsync(ws, 0, 8192, stream);
    hipMemsetAsync(ws + WS_HBUF0, 0, 512 * 1024, stream);

    detect_kernel<<<16, 256, 0, stream>>>(x, (int*)(ws + WS_FLAG));
    wxb_kernel<<<160, 256, 0, stream>>>(Wxg, bg, Wxi, bi, Wxf, bf_, Wxo, bo,
                                        (float*)(ws + WS_WXB));

    const unsigned int smem_bytes = 98304;   // forces 1 block/CU (pigeonhole: 32/XCD)
    hipFuncSetAttribute((const void*)lstm_main,
                        hipFuncAttributeMaxDynamicSharedMemorySize, (int)smem_bytes);

    void* args[] = { (void*)&x, (void*)&Whg, (void*)&Whi, (void*)&Whf, (void*)&Who, (void*)&ws };
    hipError_t err = hipLaunchCooperativeKernel((const void*)lstm_main, dim3(256), dim3(256),
                                                args, smem_bytes, stream);
    if (err != hipSuccess) {
        lstm_main<<<dim3(256), dim3(256), smem_bytes, stream>>>(x, Whg, Whi, Whf, Who, ws);
    }

    proj_kernel<<<256, 256, 0, stream>>>((const float*)(ws + WS_HFINAL), Wp, bp, out);
}